// Round 4
// baseline (219.789 us; speedup 1.0000x reference)
//
#include <hip/hip_runtime.h>
#include <hip/hip_bf16.h>
#include <math.h>

// Problem constants: B=16,H=14,W=14,D=512, L=32, HID=512, A=512
// Inputs fp32, outputs fp32 (per reference dtypes; comparison is done on a
// bf16-demoted ref — see R3 post-mortem).
#define Bn   16
#define Ln   32
#define Pn   196      // H*W
#define Dn   512
#define An   512
#define HIDn 512
#define BLn  (Bn*Ln)  // 512

// One block per (b,l): hlin -> scores -> softmax -> attn(out) -> ctx -> co_att(out)
__global__ __launch_bounds__(256) void coatt_fused_kernel(
    const float* __restrict__ maps, const float* __restrict__ hiddens,
    const float* __restrict__ W_hidden, const float* __restrict__ b_hidden,
    const float* __restrict__ W_rect, const float* __restrict__ b_rect,
    const float* __restrict__ W_co, const float* __restrict__ b_co,
    float* __restrict__ out_co, float* __restrict__ out_attn)
{
    const int bl = blockIdx.x;       // b*L + l
    const int b  = bl / Ln;
    const int t  = threadIdx.x;

    __shared__ float sh_hid[HIDn];   // hiddens[bl, :]
    __shared__ float sh_hlin[An];
    __shared__ float sh_wrect[An];
    __shared__ float sh_attn[Pn];
    __shared__ float sh_ctx[Dn];
    __shared__ float sh_red[4];

    const float* hrow = hiddens + (size_t)bl * HIDn;
    for (int i = t; i < HIDn; i += 256) {
        sh_hid[i]   = hrow[i];
        sh_wrect[i] = W_rect[i];
    }
    __syncthreads();

    // Phase 0: hlin[a] = dot(hiddens[bl,:], W_hidden[a,:]) + b_hidden[a]
    for (int a = t; a < An; a += 256) {
        const float* w = W_hidden + (size_t)a * HIDn;
        float acc = 0.f;
        for (int k = 0; k < HIDn; k += 4) {
            const float4 u = *reinterpret_cast<const float4*>(w + k);
            acc += u.x*sh_hid[k+0] + u.y*sh_hid[k+1]
                 + u.z*sh_hid[k+2] + u.w*sh_hid[k+3];
        }
        sh_hlin[a] = acc + b_hidden[a];
    }
    __syncthreads();

    const float* fb = maps + (size_t)b * Pn * Dn;   // fmaps for batch b, (P, D)

    // Phase 1: scores (one pixel p per thread; threads >= Pn idle)
    float score = -INFINITY;
    if (t < Pn) {
        const float* frow = fb + (size_t)t * Dn;
        float acc = 0.f;
        for (int a = 0; a < An; a += 4) {
            const float4 u = *reinterpret_cast<const float4*>(frow + a);
            acc += fmaxf(u.x + sh_hlin[a+0], 0.f) * sh_wrect[a+0];
            acc += fmaxf(u.y + sh_hlin[a+1], 0.f) * sh_wrect[a+1];
            acc += fmaxf(u.z + sh_hlin[a+2], 0.f) * sh_wrect[a+2];
            acc += fmaxf(u.w + sh_hlin[a+3], 0.f) * sh_wrect[a+3];
        }
        score = acc + b_rect[0];
    }

    // Phase 2: softmax over P within the block (4 waves of 64)
    float v = score;
    for (int off = 32; off > 0; off >>= 1) v = fmaxf(v, __shfl_down(v, off));
    if ((t & 63) == 0) sh_red[t >> 6] = v;
    __syncthreads();
    const float smax = fmaxf(fmaxf(sh_red[0], sh_red[1]), fmaxf(sh_red[2], sh_red[3]));
    const float e = (t < Pn) ? __expf(score - smax) : 0.f;
    __syncthreads();   // sh_red reads done before reuse
    float s = e;
    for (int off = 32; off > 0; off >>= 1) s += __shfl_down(s, off);
    if ((t & 63) == 0) sh_red[t >> 6] = s;
    __syncthreads();
    const float inv = 1.f / (sh_red[0] + sh_red[1] + sh_red[2] + sh_red[3]);
    if (t < Pn) {
        const float at = e * inv;
        sh_attn[t] = at;
        out_attn[(size_t)bl*Pn + t] = at;
    }
    __syncthreads();

    // Phase 3: ctx[d] = sum_p attn[p] * fmaps[b,p,d]  (2 consecutive d per thread)
    {
        const int d0 = t * 2;
        float acc0 = 0.f, acc1 = 0.f;
        for (int p = 0; p < Pn; ++p) {
            const float2 u = *reinterpret_cast<const float2*>(fb + (size_t)p*Dn + d0);
            const float w = sh_attn[p];
            acc0 += w * u.x;
            acc1 += w * u.y;
        }
        sh_ctx[d0]   = acc0;
        sh_ctx[d0+1] = acc1;
    }
    __syncthreads();

    // Phase 4: co_att[h] = (dot(ctx, W_co[h,:]) + b_co[h]) * hiddens[bl,h]
    for (int h = t; h < HIDn; h += 256) {
        const float* w = W_co + (size_t)h * Dn;
        float acc = 0.f;
        for (int d = 0; d < Dn; d += 4) {
            const float4 u = *reinterpret_cast<const float4*>(w + d);
            acc += u.x*sh_ctx[d+0] + u.y*sh_ctx[d+1]
                 + u.z*sh_ctx[d+2] + u.w*sh_ctx[d+3];
        }
        out_co[(size_t)bl*HIDn + h] = (acc + b_co[h]) * sh_hid[h];
    }
}

extern "C" void kernel_launch(void* const* d_in, const int* in_sizes, int n_in,
                              void* d_out, int out_size, void* d_ws, size_t ws_size,
                              hipStream_t stream)
{
    const float* maps     = (const float*)d_in[0];
    const float* hiddens  = (const float*)d_in[1];
    const float* W_hidden = (const float*)d_in[2];
    const float* b_hidden = (const float*)d_in[3];
    const float* W_rect   = (const float*)d_in[4];
    const float* b_rect   = (const float*)d_in[5];
    const float* W_co     = (const float*)d_in[6];
    const float* b_co     = (const float*)d_in[7];

    float* out_co   = (float*)d_out;                     // (B,L,HID) = 262144 elems
    float* out_attn = out_co + (size_t)BLn * HIDn;       // (B,L,P)   = 100352 elems

    hipLaunchKernelGGL(coatt_fused_kernel, dim3(BLn), dim3(256), 0, stream,
                       maps, hiddens, W_hidden, b_hidden, W_rect, b_rect,
                       W_co, b_co, out_co, out_attn);
}

// Round 5
// 147.065 us; speedup vs baseline: 1.4945x; 1.4945x over previous
//
#include <hip/hip_runtime.h>
#include <hip/hip_bf16.h>
#include <math.h>

// B=16,H=14,W=14,D=512, L=32, HID=512, A=512. fp32 in/out.
#define Bn   16
#define Ln   32
#define Pn   196
#define Dn   512
#define BLn  512

// ---------------- K1/K5: split-K NT GEMM: C += A(M,K) * B(N,K)^T ----------------
// M=N=K=512. Tile 64x64, k-chunk 128, grid (8,8,4), 256 threads.
// LDS stores fragments transposed ([k][m]) so inner loop uses ds_read_b128.
template<bool ADD_BIAS>
__global__ __launch_bounds__(256) void gemm_nt_splitk(
    const float* __restrict__ A, const float* __restrict__ B,
    const float* __restrict__ bias, float* __restrict__ C)
{
    const int m0 = blockIdx.x * 64, n0 = blockIdx.y * 64, k0 = blockIdx.z * 128;
    const int tid = threadIdx.x;

    __shared__ float As[128][68];   // [k][m], row 272 B (16-B aligned)
    __shared__ float Bs[128][68];

    // stage 64x128 of A and B, transposed into LDS
    for (int i = 0; i < 8; ++i) {
        const int fidx = i * 256 + tid;        // 0..2047 float4s
        const int r  = fidx >> 5;              // 0..63 (row within tile)
        const int c4 = fidx & 31;              // 0..31 (float4 within k-chunk)
        const float4 a = *reinterpret_cast<const float4*>(A + (size_t)(m0 + r) * 512 + k0 + c4 * 4);
        const float4 b = *reinterpret_cast<const float4*>(B + (size_t)(n0 + r) * 512 + k0 + c4 * 4);
        const int kk = c4 * 4;
        As[kk+0][r] = a.x; As[kk+1][r] = a.y; As[kk+2][r] = a.z; As[kk+3][r] = a.w;
        Bs[kk+0][r] = b.x; Bs[kk+1][r] = b.y; Bs[kk+2][r] = b.z; Bs[kk+3][r] = b.w;
    }
    __syncthreads();

    const int tx = tid & 15, ty = tid >> 4;    // 16x16 thread grid, 4x4 outputs each
    float acc[4][4];
    #pragma unroll
    for (int i = 0; i < 4; ++i)
        #pragma unroll
        for (int j = 0; j < 4; ++j) acc[i][j] = 0.f;

    for (int k = 0; k < 128; ++k) {
        const float4 av = *reinterpret_cast<const float4*>(&As[k][ty * 4]); // broadcast (4 addrs)
        const float4 bv = *reinterpret_cast<const float4*>(&Bs[k][tx * 4]); // 2-way (free)
        const float a0 = av.x, a1 = av.y, a2 = av.z, a3 = av.w;
        const float b0 = bv.x, b1 = bv.y, b2 = bv.z, b3 = bv.w;
        acc[0][0] += a0*b0; acc[0][1] += a0*b1; acc[0][2] += a0*b2; acc[0][3] += a0*b3;
        acc[1][0] += a1*b0; acc[1][1] += a1*b1; acc[1][2] += a1*b2; acc[1][3] += a1*b3;
        acc[2][0] += a2*b0; acc[2][1] += a2*b1; acc[2][2] += a2*b2; acc[2][3] += a2*b3;
        acc[3][0] += a3*b0; acc[3][1] += a3*b1; acc[3][2] += a3*b2; acc[3][3] += a3*b3;
    }

    #pragma unroll
    for (int i = 0; i < 4; ++i) {
        const int m = m0 + ty * 4 + i;
        #pragma unroll
        for (int j = 0; j < 4; ++j) {
            const int n = n0 + tx * 4 + j;
            float v = acc[i][j];
            if (ADD_BIAS && blockIdx.z == 0) v += bias[n];
            atomicAdd(&C[(size_t)m * 512 + n], v);
        }
    }
}

// ---------------- K2: raw scores ----------------
// grid (16 b, 14 ptiles), 256 threads: tid = kc*32 + l (kc: a-chunk of 64, l: 0..31)
__global__ __launch_bounds__(256) void scores_kernel(
    const float* __restrict__ maps, const float* __restrict__ hlin,
    const float* __restrict__ W_rect, const float* __restrict__ b_rect,
    float* __restrict__ scores_out)
{
    const int b = blockIdx.x, p0 = blockIdx.y * 14;
    const int tid = threadIdx.x;
    const int kc = tid >> 5, l = tid & 31;

    __shared__ float fls[14][516];     // fmaps tile   (row 2064 B, 16-B aligned)
    __shared__ float hls[32][516];     // hlin rows for this b
    __shared__ float wls[516];
    __shared__ float red[4][14][32];

    const float* fbase = maps + ((size_t)b * Pn + p0) * 512;
    for (int i = 0; i < 7; ++i) {                       // 14*512/4 = 1792 float4
        const int fidx = i * 256 + tid;
        const int e = fidx * 4, p = e >> 9, c = e & 511;
        *reinterpret_cast<float4*>(&fls[p][c]) = *reinterpret_cast<const float4*>(fbase + (size_t)p * 512 + c);
    }
    const float* hbase = hlin + (size_t)b * 32 * 512;
    for (int i = 0; i < 16; ++i) {                      // 32*512/4 = 4096 float4
        const int fidx = i * 256 + tid;
        const int e = fidx * 4, r = e >> 9, c = e & 511;
        *reinterpret_cast<float4*>(&hls[r][c]) = *reinterpret_cast<const float4*>(hbase + (size_t)r * 512 + c);
    }
    if (tid < 128)
        *reinterpret_cast<float4*>(&wls[tid * 4]) = *reinterpret_cast<const float4*>(W_rect + tid * 4);
    __syncthreads();

    float acc[14];
    #pragma unroll
    for (int p = 0; p < 14; ++p) acc[p] = 0.f;

    const int off = kc * 64;
    for (int j4 = 0; j4 < 16; ++j4) {
        const float4 w4 = *reinterpret_cast<const float4*>(&wls[off + j4 * 4]);
        const float4 h4 = *reinterpret_cast<const float4*>(&hls[l][off + j4 * 4]);
        #pragma unroll
        for (int p = 0; p < 14; ++p) {
            const float4 f4 = *reinterpret_cast<const float4*>(&fls[p][off + j4 * 4]);
            acc[p] += fmaxf(f4.x + h4.x, 0.f) * w4.x + fmaxf(f4.y + h4.y, 0.f) * w4.y
                    + fmaxf(f4.z + h4.z, 0.f) * w4.z + fmaxf(f4.w + h4.w, 0.f) * w4.w;
        }
    }

    // reduce over kc: pair within wave (kc, kc+1 are lanes l and l+32)
    #pragma unroll
    for (int p = 0; p < 14; ++p) acc[p] += __shfl_down(acc[p], 32);
    const int wave = tid >> 6;
    if ((tid & 63) < 32) {
        #pragma unroll
        for (int p = 0; p < 14; ++p) red[wave][p][l] = acc[p];
    }
    __syncthreads();

    const float br = b_rect[0];
    const int l2 = tid & 31, pb = tid >> 5;   // pb 0..7
    for (int pp = pb; pp < 14; pp += 8) {
        const float s = red[0][pp][l2] + red[1][pp][l2] + red[2][pp][l2] + red[3][pp][l2] + br;
        scores_out[((size_t)b * 32 + l2) * Pn + p0 + pp] = s;
    }
}

// ---------------- K3: softmax in place over P=196 ----------------
__global__ __launch_bounds__(64) void softmax_kernel(float* __restrict__ attn)
{
    const int row = blockIdx.x;
    const int lane = threadIdx.x;
    float* base = attn + (size_t)row * Pn;

    float v[4];
    #pragma unroll
    for (int i = 0; i < 4; ++i) {
        const int p = lane + 64 * i;
        v[i] = (p < Pn) ? base[p] : -INFINITY;
    }
    float m = fmaxf(fmaxf(v[0], v[1]), fmaxf(v[2], v[3]));
    for (int off = 32; off > 0; off >>= 1) m = fmaxf(m, __shfl_down(m, off));
    m = __shfl(m, 0);
    float e[4]; float s = 0.f;
    #pragma unroll
    for (int i = 0; i < 4; ++i) {
        const int p = lane + 64 * i;
        e[i] = (p < Pn) ? __expf(v[i] - m) : 0.f;
        s += e[i];
    }
    for (int off = 32; off > 0; off >>= 1) s += __shfl_down(s, off);
    s = __shfl(s, 0);
    const float inv = 1.f / s;
    #pragma unroll
    for (int i = 0; i < 4; ++i) {
        const int p = lane + 64 * i;
        if (p < Pn) base[p] = e[i] * inv;
    }
}

// ---------------- K4: ctx = attn @ fmaps ----------------
// grid (16 b, 16 d-tiles of 32), 256 threads: tid = l*8 + d4
__global__ __launch_bounds__(256) void ctx_kernel(
    const float* __restrict__ maps, const float* __restrict__ attn,
    float* __restrict__ ctx)
{
    const int b = blockIdx.x, d0 = blockIdx.y * 32;
    const int tid = threadIdx.x;
    const int l = tid >> 3, d4 = tid & 7;

    __shared__ float ft[196][36];     // row 144 B, aligned
    __shared__ float at[32][204];     // row 816 B, aligned; 12-bank rotation

    const float* fbase = maps + (size_t)b * Pn * 512 + d0;
    for (int fidx = tid; fidx < 1568; fidx += 256) {    // 196*32/4
        const int p = fidx >> 3, q = fidx & 7;
        *reinterpret_cast<float4*>(&ft[p][q * 4]) = *reinterpret_cast<const float4*>(fbase + (size_t)p * 512 + q * 4);
    }
    const float* abase = attn + (size_t)b * 32 * Pn;
    for (int idx = tid; idx < 32 * Pn; idx += 256) {
        const int r = idx / Pn, p = idx - r * Pn;
        at[r][p] = abase[idx];
    }
    __syncthreads();

    float ax = 0.f, ay = 0.f, az = 0.f, aw = 0.f;
    for (int p4 = 0; p4 < 49; ++p4) {
        const float4 a4 = *reinterpret_cast<const float4*>(&at[l][p4 * 4]);
        const float4 f0 = *reinterpret_cast<const float4*>(&ft[p4 * 4 + 0][d4 * 4]);
        const float4 f1 = *reinterpret_cast<const float4*>(&ft[p4 * 4 + 1][d4 * 4]);
        const float4 f2 = *reinterpret_cast<const float4*>(&ft[p4 * 4 + 2][d4 * 4]);
        const float4 f3 = *reinterpret_cast<const float4*>(&ft[p4 * 4 + 3][d4 * 4]);
        ax += a4.x * f0.x + a4.y * f1.x + a4.z * f2.x + a4.w * f3.x;
        ay += a4.x * f0.y + a4.y * f1.y + a4.z * f2.y + a4.w * f3.y;
        az += a4.x * f0.z + a4.y * f1.z + a4.z * f2.z + a4.w * f3.z;
        aw += a4.x * f0.w + a4.y * f1.w + a4.z * f2.w + a4.w * f3.w;
    }
    float4 out; out.x = ax; out.y = ay; out.z = az; out.w = aw;
    *reinterpret_cast<float4*>(ctx + ((size_t)b * 32 + l) * 512 + d0 + d4 * 4) = out;
}

// ---------------- K6: epilogue out = (acc + b_co) * hiddens, in place ----------------
__global__ __launch_bounds__(256) void epilogue_kernel(
    float* __restrict__ out_co, const float* __restrict__ b_co,
    const float* __restrict__ hiddens)
{
    const int idx = blockIdx.x * 256 + threadIdx.x;     // float4 index, 65536 total
    const int n4 = idx & 127;
    float4 v = *reinterpret_cast<float4*>(out_co + (size_t)idx * 4);
    const float4 bc = *reinterpret_cast<const float4*>(b_co + n4 * 4);
    const float4 hd = *reinterpret_cast<const float4*>(hiddens + (size_t)idx * 4);
    v.x = (v.x + bc.x) * hd.x; v.y = (v.y + bc.y) * hd.y;
    v.z = (v.z + bc.z) * hd.z; v.w = (v.w + bc.w) * hd.w;
    *reinterpret_cast<float4*>(out_co + (size_t)idx * 4) = v;
}

extern "C" void kernel_launch(void* const* d_in, const int* in_sizes, int n_in,
                              void* d_out, int out_size, void* d_ws, size_t ws_size,
                              hipStream_t stream)
{
    const float* maps     = (const float*)d_in[0];
    const float* hiddens  = (const float*)d_in[1];
    const float* W_hidden = (const float*)d_in[2];
    const float* b_hidden = (const float*)d_in[3];
    const float* W_rect   = (const float*)d_in[4];
    const float* b_rect   = (const float*)d_in[5];
    const float* W_co     = (const float*)d_in[6];
    const float* b_co     = (const float*)d_in[7];

    float* out_co   = (float*)d_out;                    // (512,512); doubles as hlin then GEMM acc
    float* out_attn = out_co + (size_t)BLn * 512;       // (512,196); raw scores then attn
    float* ctx      = (float*)d_ws;                     // (512,512) = 1 MB scratch

    // 1) hlin = hiddens @ W_hidden^T + b_hidden  -> out_co
    hipMemsetAsync(out_co, 0, (size_t)BLn * 512 * sizeof(float), stream);
    hipLaunchKernelGGL((gemm_nt_splitk<true>), dim3(8, 8, 4), dim3(256), 0, stream,
                       hiddens, W_hidden, b_hidden, out_co);
    // 2) raw scores -> out_attn
    hipLaunchKernelGGL(scores_kernel, dim3(Bn, 14), dim3(256), 0, stream,
                       maps, out_co, W_rect, b_rect, out_attn);
    // 3) softmax in place
    hipLaunchKernelGGL(softmax_kernel, dim3(BLn), dim3(64), 0, stream, out_attn);
    // 4) ctx = attn @ fmaps -> ws
    hipLaunchKernelGGL(ctx_kernel, dim3(Bn, 16), dim3(256), 0, stream,
                       maps, out_attn, ctx);
    // 5) out_co = ctx @ W_co^T (accumulated), then epilogue
    hipMemsetAsync(out_co, 0, (size_t)BLn * 512 * sizeof(float), stream);
    hipLaunchKernelGGL((gemm_nt_splitk<false>), dim3(8, 8, 4), dim3(256), 0, stream,
                       ctx, W_co, (const float*)nullptr, out_co);
    hipLaunchKernelGGL(epilogue_kernel, dim3(256), dim3(256), 0, stream,
                       out_co, b_co, hiddens);
}